// Round 3
// baseline (1349.271 us; speedup 1.0000x reference)
//
#include <hip/hip_runtime.h>

#define SS 512
#define BB 2048
#define DD 128
#define HH 8
#define TS 64   // s-chunk per kconv block

// ---- DPP helper (compile-time ctrl) ----
template<int CTRL>
__device__ __forceinline__ float dppf(float old_, float src) {
  return __int_as_float(__builtin_amdgcn_update_dpp(
      __float_as_int(old_), __float_as_int(src), CTRL, 0xF, 0xF, false));
}

// value from lane^32 (cross-half swap, VALU-speed on gfx950)
__device__ __forceinline__ float xorswap32(float v, bool hi) {
#if __has_builtin(__builtin_amdgcn_permlane32_swap)
  auto r = __builtin_amdgcn_permlane32_swap(__float_as_int(v), __float_as_int(v), false, false);
  struct { int a, b; } s2;
  __builtin_memcpy(&s2, &r, 8);
  // ret0 lanes>=32 = old[0:31]; ret1 lanes<32 = old[32:63]
  return __int_as_float(hi ? s2.a : s2.b);
#else
  return __shfl_xor(v, 32);
#endif
}

// ---------------- conv1d (SAME, k=3, no bias): enc[s][b][h] ----------------
// Block: 256 thr = 4 waves; wave = 2 b's (lane halves); half-lane hl: h = hl&7,
// d-chunk = hl>>3 (32 floats each). Streaming-k: row r updates accs for
// enc[r-1](w2), enc[r](w1), enc[r+1](w0). x read once, coalesced/broadcast.
__global__ __launch_bounds__(256) void kconv(const float* __restrict__ x,
                                             const float* __restrict__ cw,
                                             float* __restrict__ enc) {
  __shared__ float wl[3][8][132];   // [k][h][d] padded to 132
  const int tid = threadIdx.x;
  for (int i = tid; i < 3 * DD * HH; i += 256) {
    int h = i / 384;
    int rem = i - h * 384;
    int d = rem / 3;
    int k = rem - d * 3;
    wl[k][h][d] = cw[i];            // cw layout [h][d][k]
  }
  __syncthreads();

  const int lane = tid & 63;
  const int hl   = lane & 31;
  const int h    = hl & 7;
  const int dc   = hl >> 3;
  const int wv   = tid >> 6;
  const int b    = blockIdx.x * 8 + wv * 2 + (lane >> 5);
  const int c0   = blockIdx.y * TS;
  const int dbase = dc * 32;

  auto loadrow = [&](int r, float4 (&xb)[8]) {
    if (r >= 0 && r < SS) {
      const float4* p = (const float4*)(x + ((size_t)r * BB + b) * DD + dbase);
      #pragma unroll
      for (int j = 0; j < 8; ++j) xb[j] = p[j];
    } else {
      #pragma unroll
      for (int j = 0; j < 8; ++j) xb[j] = make_float4(0.f, 0.f, 0.f, 0.f);
    }
  };

  auto dorow = [&](const float4 (&xb)[8], float& am, float& a0, float& ap) {
    #pragma unroll
    for (int j = 0; j < 8; ++j) {
      float4 xv = xb[j];
      float4 w0 = *(const float4*)&wl[0][h][dbase + 4 * j];
      float4 w1 = *(const float4*)&wl[1][h][dbase + 4 * j];
      float4 w2 = *(const float4*)&wl[2][h][dbase + 4 * j];
      ap = fmaf(xv.x, w0.x, ap); a0 = fmaf(xv.x, w1.x, a0); am = fmaf(xv.x, w2.x, am);
      ap = fmaf(xv.y, w0.y, ap); a0 = fmaf(xv.y, w1.y, a0); am = fmaf(xv.y, w2.y, am);
      ap = fmaf(xv.z, w0.z, ap); a0 = fmaf(xv.z, w1.z, a0); am = fmaf(xv.z, w2.z, am);
      ap = fmaf(xv.w, w0.w, ap); a0 = fmaf(xv.w, w1.w, a0); am = fmaf(xv.w, w2.w, am);
    }
  };

  auto redstore = [&](float v, int rout) {
    float v2 = v + dppf<0x128>(v, v);                                  // xor8 (row_ror:8)
    v2 = v2 + __int_as_float(
        __builtin_amdgcn_ds_swizzle(__float_as_int(v2), 0x401F));      // xor16
    if (hl < 8) enc[((size_t)rout * BB + b) * 8 + h] = v2;
  };

  float am = 0.f, a0 = 0.f, ap = 0.f;
  float4 xA[8], xB[8];
  int r = c0 - 1;
  loadrow(r, xA);

  auto phase = [&](float4 (&xu)[8], float4 (&xl)[8], float& Am, float& A0, float& Ap) {
    int rn = r + 1;
    loadrow(rn <= c0 + TS ? rn : -1, xl);
    dorow(xu, Am, A0, Ap);
    if (r > c0) redstore(Am, r - 1);
    Am = 0.f;
    ++r;
  };

  for (int it = 0; it < 11; ++it) {       // 66 rows: c0-1 .. c0+TS
    phase(xA, xB, am, a0, ap);
    phase(xB, xA, a0, ap, am);
    phase(xA, xB, ap, am, a0);
    phase(xB, xA, am, a0, ap);
    phase(xA, xB, a0, ap, am);
    phase(xB, xA, ap, am, a0);
  }
}

// ---------------- recurrent QLSTM scan ----------------
// Lane layout (64 thr/block = 1 wave, 2 b's):
//   [0-7]=b0F [8-15]=b0I [16-23]=b1F [24-31]=b1I [32-39]=b0G [40-47]=b0O [48-55]=b1G [56-63]=b1O
// gate^1 = xor8 (DPP row_ror:8), gate^2 = xor32 (permlane32_swap). q ops stay 8-aligned DPP.
__global__ __launch_bounds__(64) void krec(
    const float* __restrict__ ln_g, const float* __restrict__ ln_b,
    const float* __restrict__ Wf, const float* __restrict__ bf,
    const float* __restrict__ Wi, const float* __restrict__ bi,
    const float* __restrict__ Wg, const float* __restrict__ bg,
    const float* __restrict__ Wo, const float* __restrict__ bo,
    float* __restrict__ out)
{
  const int lane = threadIdx.x;
  const int q    = lane & 7;
  const int gb0i = (lane >> 3) & 1;
  const int gb1i = (lane >> 5) & 1;
  const int gate = gb1i * 2 + gb0i;
  const int b    = blockIdx.x * 2 + ((lane >> 4) & 1);
  const bool gb0 = gb0i != 0, gb1 = gb1i != 0;

  const float* Wm = (gate == 0) ? Wf : (gate == 1) ? Wi : (gate == 2) ? Wg : Wo;
  const float* bm = (gate == 0) ? bf : (gate == 1) ? bi : (gate == 2) ? bg : bo;

  float wraw[16];
  #pragma unroll
  for (int j = 0; j < 16; ++j) wraw[j] = Wm[q * 16 + j];
  float SWp = 0.f, bb = bm[q];
  #pragma unroll
  for (int j = 0; j < 16; ++j) {
    SWp += wraw[j] * ln_g[j];
    bb  = fmaf(ln_b[j], wraw[j], bb);
  }
  float wx[8], wh[8];
  #pragma unroll
  for (int j = 0; j < 8; ++j) wx[j] = wraw[j] * ln_g[j];
  #pragma unroll
  for (int k = 0; k < 8; ++k) { int src = 8 + (q ^ k); wh[k] = wraw[src] * ln_g[src]; }

  const bool  isG  = (gate == 2);
  const float ymul = isG ? 2.f : 1.f;

  float h_own = 0.f, c_own = 0.f;
  float r0=0.f,r1=0.f,r2=0.f,r3=0.f,r4=0.f,r5=0.f,r6=0.f,r7=0.f;

  const float4* pe = (const float4*)out;
  size_t base = (size_t)b * 2;
  float4 A0 = pe[base],            A1 = pe[base + 1];
  float4 B0 = pe[base + BB*2],     B1 = pe[base + BB*2 + 1];
  float4 C0 = pe[base + BB*4],     C1 = pe[base + BB*4 + 1];
  size_t nxt = base + BB*6;
  float* pst = out + (size_t)b * 8 + q;

  auto step = [&](float4& u0, float4& u1, int s) {
    const float x0=u0.x, x1=u0.y, x2=u0.z, x3=u0.w;
    const float x4=u1.x, x5=u1.y, x6=u1.z, x7=u1.w;
    if (s + 3 < SS) { u0 = pe[nxt]; u1 = pe[nxt + 1]; nxt += BB*2; }   // 3-deep prefetch
    // LayerNorm stats over [x(8), h(8)]
    float sv = (((x0+x1)+(x2+x3)) + ((x4+x5)+(x6+x7)))
             + (((r0+r1)+(r2+r3)) + ((r4+r5)+(r6+r7)));
    float qa = fmaf(x0,x0, x1*x1) + fmaf(x2,x2, x3*x3);
    float qb = fmaf(x4,x4, x5*x5) + fmaf(x6,x6, x7*x7);
    float qc = fmaf(r1,r1, r0*r0) + fmaf(r3,r3, r2*r2);
    float qd = fmaf(r5,r5, r4*r4) + fmaf(r7,r7, r6*r6);
    float sq  = (qa + qb) + (qc + qd);
    float mu  = sv * 0.0625f;
    float var = fmaf(-mu, mu, sq * 0.0625f);
    float rinv = __builtin_amdgcn_rsqf(var + 1e-5f);
    // dot(v, W') — shallow trees
    float d0  = fmaf(x0,wx[0], x1*wx[1]);
    float d0b = fmaf(x2,wx[2], x3*wx[3]);
    float d1  = fmaf(x4,wx[4], x5*wx[5]);
    float d1b = fmaf(x6,wx[6], x7*wx[7]);
    float d2  = fmaf(r0,wh[0], r1*wh[1]);
    float d2b = fmaf(r2,wh[2], r3*wh[3]);
    float d3  = fmaf(r4,wh[4], r5*wh[5]);
    float d3b = fmaf(r6,wh[6], r7*wh[7]);
    float dot = ((d0+d0b)+(d1+d1b)) + ((d2+d2b)+(d3+d3b));
    float theta = fmaf(fmaf(-mu, SWp, dot), rinv, bb);
    float c = __cosf(theta);
    // _qexp: Kogge-Stone cumprod over q (8-lane groups), DPP + q-mask
    float cp = (q == 0) ? 1.f : c;
    float t;
    t = dppf<0x111>(cp, cp); cp = (q >= 1) ? cp * t : cp;
    t = dppf<0x112>(cp, cp); cp = (q >= 2) ? cp * t : cp;
    t = dppf<0x114>(cp, cp); cp = (q >= 4) ? cp * t : cp;
    float cb  = dppf<0x00>(c, c);
    float cb2 = dppf<0x114>(cb, cb);
    float c0b = (q >= 4) ? cb2 : cb;
    float tot = dppf<0x141>(cp, cp);
    float outq = (q == 0) ? tot : c0b * cp;
    // activation
    float e  = __expf(-(outq * ymul));
    float sg = __builtin_amdgcn_rcpf(1.f + e);
    float a  = isG ? fmaf(2.f, sg, -1.f) : sg;
    // gather the four gates for this q: ^1 via DPP, ^2/^3 via permlane32_swap
    float t1 = dppf<0x128>(a, a);
    float t2 = xorswap32(a, gb1);
    float t3 = xorswap32(t1, gb1);
    float v01  = gb0 ? t1 : a;
    float v23  = gb0 ? t3 : t2;
    float v01i = gb0 ? a  : t1;
    float v23i = gb0 ? t2 : t3;
    float fv = gb1 ? v23  : v01;
    float gv = gb1 ? v01  : v23;
    float iv = gb1 ? v23i : v01i;
    float ov = gb1 ? v01i : v23i;
    // state update
    c_own = fmaf(fv, c_own, iv * gv);
    float e2 = __expf(-2.f * c_own);
    float th = fmaf(2.f, __builtin_amdgcn_rcpf(1.f + e2), -1.f);
    h_own = ov * th;
    if (gate == 0) *pst = h_own;
    pst += BB * HH;
    // butterfly all-gather of h within 8-lane q-group: r[k] = h[q^k]
    r0 = h_own;
    r1 = dppf<0xB1>(r0, r0);
    r2 = dppf<0x4E>(r0, r0);
    r3 = dppf<0x4E>(r1, r1);
    float m0 = dppf<0x141>(r0, r0);
    float m1 = dppf<0x141>(r1, r1);
    float m2 = dppf<0x141>(r2, r2);
    float m3 = dppf<0x141>(r3, r3);
    r4 = dppf<0x1B>(m0, m0);
    r5 = dppf<0x1B>(m1, m1);
    r6 = dppf<0x1B>(m2, m2);
    r7 = dppf<0x1B>(m3, m3);
  };

  for (int s = 0; s < 510; s += 3) {
    step(A0, A1, s);
    step(B0, B1, s + 1);
    step(C0, C1, s + 2);
  }
  step(A0, A1, 510);
  step(B0, B1, 511);

  if (gate == 0) {
    out[(size_t)SS * BB * HH + (size_t)b * HH + q] = h_own;                       // hx
    out[(size_t)SS * BB * HH + (size_t)BB * HH + (size_t)b * HH + q] = c_own;     // cx
  }
}

extern "C" void kernel_launch(void* const* d_in, const int* in_sizes, int n_in,
                              void* d_out, int out_size, void* d_ws, size_t ws_size,
                              hipStream_t stream) {
  const float* x   = (const float*)d_in[0];
  const float* cw  = (const float*)d_in[1];
  const float* lng = (const float*)d_in[2];
  const float* lnb = (const float*)d_in[3];
  const float* Wf_ = (const float*)d_in[4];
  const float* bf_ = (const float*)d_in[5];
  const float* Wi_ = (const float*)d_in[6];
  const float* bi_ = (const float*)d_in[7];
  const float* Wg_ = (const float*)d_in[8];
  const float* bg_ = (const float*)d_in[9];
  const float* Wo_ = (const float*)d_in[10];
  const float* bo_ = (const float*)d_in[11];
  float* out = (float*)d_out;

  kconv<<<dim3(BB / 8, SS / TS), 256, 0, stream>>>(x, cw, out);
  krec<<<BB / 2, 64, 0, stream>>>(lng, lnb, Wf_, bf_, Wi_, bi_, Wg_, bg_, Wo_, bo_, out);
}